// Round 3
// baseline (431.464 us; speedup 1.0000x reference)
//
#include <hip/hip_runtime.h>
#include <math.h>

#define C_OLD 23
#define G 10
#define BVAL 8
#define NVAL 262144                 // 2^18 rows per b
#define BLOCK 256
#define ROWS_PER_TILE 256
#define TILES 8
#define BLOCKS_PER_B 128            // 128 blocks * 8 tiles * 256 rows = 262144
#define NBLOCKS (BVAL * BLOCKS_PER_B)          // 1024
#define TILE_FLOATS (ROWS_PER_TILE * C_OLD)    // 5888 floats = 23552 B
#define TILE_VEC4   (TILE_FLOATS / 4)          // 1472
#define REM_VEC4    (TILE_VEC4 - 5 * BLOCK)    // 192

// ws layout: part[(b*G + g) * BLOCKS_PER_B + blk] -> 80*128 floats = 40960 B
//            then unsigned counter at byte 40960 (zeroed via hipMemsetAsync)
#define COUNTER_OFF 40960

__global__ __launch_bounds__(BLOCK) void grouped_kl_kernel(
        const float* __restrict__ in, const float* __restrict__ tgt,
        float* __restrict__ part, unsigned int* __restrict__ counter,
        float* __restrict__ out) {
    __shared__ float tile[TILE_FLOATS];
    __shared__ float wpart[BLOCK / 64][G];
    __shared__ unsigned int isLast;
    __shared__ double red[128];

    const int tid = threadIdx.x;
    const int b   = blockIdx.x / BLOCKS_PER_B;
    const int blk = blockIdx.x % BLOCKS_PER_B;
    const long long rowBase = (long long)b * NVAL
                            + (long long)blk * (ROWS_PER_TILE * TILES);

    float acc[G];
    #pragma unroll
    for (int g = 0; g < G; ++g) acc[g] = 0.0f;

    float4 r0, r1, r2, r3, r4, r5;
    float4* dstv = (float4*)tile;

    // ---- prologue: load tile 0 -> regs -> LDS ----
    {
        const float4* src = (const float4*)(in + rowBase * C_OLD);
        r0 = src[tid];              r1 = src[tid + 1 * BLOCK];
        r2 = src[tid + 2 * BLOCK];  r3 = src[tid + 3 * BLOCK];
        r4 = src[tid + 4 * BLOCK];
        if (tid < REM_VEC4) r5 = src[tid + 5 * BLOCK];
        dstv[tid] = r0;             dstv[tid + 1 * BLOCK] = r1;
        dstv[tid + 2 * BLOCK] = r2; dstv[tid + 3 * BLOCK] = r3;
        dstv[tid + 4 * BLOCK] = r4;
        if (tid < REM_VEC4) dstv[tid + 5 * BLOCK] = r5;
    }
    __syncthreads();

    for (int t = 0; t < TILES; ++t) {
        // ---- prefetch tile t+1 into registers (loads in flight during compute) ----
        if (t + 1 < TILES) {
            const float4* src = (const float4*)(
                in + (rowBase + (long long)(t + 1) * ROWS_PER_TILE) * C_OLD);
            r0 = src[tid];              r1 = src[tid + 1 * BLOCK];
            r2 = src[tid + 2 * BLOCK];  r3 = src[tid + 3 * BLOCK];
            r4 = src[tid + 4 * BLOCK];
            if (tid < REM_VEC4) r5 = src[tid + 5 * BLOCK];
        }

        // ---- per-row group sums + normalize (stride-23 LDS: <=2-way, free) ----
        const float* row = tile + tid * C_OLD;
        float s0 = row[0] + row[1];
        float s1 = row[2] + row[3];
        float s2 = row[4] + row[5] + row[6];
        float s3 = row[7] + row[8];
        float s4 = row[9] + row[10] + row[11];
        float s5 = row[12] + row[13];
        float s6 = row[14] + row[15] + row[16];
        float s7 = row[17] + row[18];
        float s8 = row[19] + row[20];
        float s9 = row[21] + row[22];
        float tot = ((s0 + s1) + (s2 + s3)) + ((s4 + s5) + (s6 + s7)) + (s8 + s9);
        float inv = 1.0f / tot;
        acc[0] += s0 * inv; acc[1] += s1 * inv; acc[2] += s2 * inv;
        acc[3] += s3 * inv; acc[4] += s4 * inv; acc[5] += s5 * inv;
        acc[6] += s6 * inv; acc[7] += s7 * inv; acc[8] += s8 * inv;
        acc[9] += s9 * inv;
        __syncthreads();   // everyone done reading LDS

        if (t + 1 < TILES) {
            dstv[tid] = r0;             dstv[tid + 1 * BLOCK] = r1;
            dstv[tid + 2 * BLOCK] = r2; dstv[tid + 3 * BLOCK] = r3;
            dstv[tid + 4 * BLOCK] = r4;
            if (tid < REM_VEC4) dstv[tid + 5 * BLOCK] = r5;
            __syncthreads();
        }
    }

    // ---- block reduction, amortized over 2048 rows ----
    #pragma unroll
    for (int g = 0; g < G; ++g) {
        float v = acc[g];
        #pragma unroll
        for (int off = 32; off > 0; off >>= 1)
            v += __shfl_down(v, off, 64);
        acc[g] = v;
    }
    const int wave = tid >> 6;
    const int lane = tid & 63;
    if (lane == 0) {
        #pragma unroll
        for (int g = 0; g < G; ++g) wpart[wave][g] = acc[g];
    }
    __syncthreads();
    if (tid < G) {
        float s = wpart[0][tid] + wpart[1][tid] + wpart[2][tid] + wpart[3][tid];
        part[((long long)b * G + tid) * BLOCKS_PER_B + blk] = s;
    }

    // ---- last-block-done: fused finalize ----
    __threadfence();                       // make partials visible device-wide
    if (tid == 0) {
        unsigned int old = atomicAdd(counter, 1u);
        isLast = (old == NBLOCKS - 1) ? 1u : 0u;
    }
    __syncthreads();
    if (!isLast) return;
    __threadfence();                       // acquire: see all blocks' partials

    double term = 0.0;
    if (tid < BVAL * G) {
        const float4* p4 = (const float4*)(part + (long long)tid * BLOCKS_PER_B);
        double s = 0.0;
        #pragma unroll 8
        for (int i = 0; i < BLOCKS_PER_B / 4; ++i) {
            float4 v = p4[i];
            s += (double)v.x + (double)v.y + (double)v.z + (double)v.w;
        }
        double avg = s / (double)NVAL;     // mean prob over N
        double tv  = (double)tgt[tid];
        term = tv * (log(tv) - log(avg));
    }
    if (tid < 128) red[tid] = term;
    __syncthreads();
    #pragma unroll
    for (int s = 64; s > 0; s >>= 1) {
        if (tid < s) red[tid] += red[tid + s];
        __syncthreads();
    }
    if (tid == 0) out[0] = (float)(red[0] / (double)(G * BVAL));
}

extern "C" void kernel_launch(void* const* d_in, const int* in_sizes, int n_in,
                              void* d_out, int out_size, void* d_ws, size_t ws_size,
                              hipStream_t stream) {
    const float* inputs  = (const float*)d_in[0];   // [8, 262144, 23] f32
    const float* targets = (const float*)d_in[1];   // [8, 10] f32
    float* out  = (float*)d_out;                    // scalar f32
    float* part = (float*)d_ws;                     // 80 * 128 floats
    unsigned int* counter = (unsigned int*)((char*)d_ws + COUNTER_OFF);

    hipMemsetAsync(counter, 0, sizeof(unsigned int), stream);
    grouped_kl_kernel<<<NBLOCKS, BLOCK, 0, stream>>>(inputs, targets, part, counter, out);
}

// Round 4
// 267.789 us; speedup vs baseline: 1.6112x; 1.6112x over previous
//
#include <hip/hip_runtime.h>
#include <math.h>

#define C_OLD 23
#define G 10
#define BVAL 8
#define NVAL 262144                  // 2^18 rows per b
#define BLOCK 256
#define WAVES (BLOCK / 64)           // 4
#define ROWS_PER_CHUNK 64            // rows per wave per chunk (1 row/lane)
#define CHUNKS 8                     // chunks per wave -> 512 rows/wave, 2048/block
#define BLOCKS_PER_B 128             // 128 * 2048 = 262144 rows = N
#define NBLOCKS (BVAL * BLOCKS_PER_B)          // 1024
#define CHUNK_FLOATS (ROWS_PER_CHUNK * C_OLD)  // 1472 floats = 5888 B per wave
#define CHUNK_VEC4 (CHUNK_FLOATS / 4)          // 368 float4 per chunk

// ws layout: part[(b*G + g) * BLOCKS_PER_B + blk]  -> 80*128 floats = 40960 B
__global__ __launch_bounds__(BLOCK) void group_prob_partial_kernel(
        const float* __restrict__ in, float* __restrict__ part) {
    __shared__ float lds[WAVES][CHUNK_FLOATS];   // wave-private chunks: no barriers
    __shared__ float wpart[WAVES][G];

    const int tid  = threadIdx.x;
    const int wave = tid >> 6;
    const int lane = tid & 63;
    const int b    = blockIdx.x >> 7;                 // BLOCKS_PER_B == 128
    const int blk  = blockIdx.x & (BLOCKS_PER_B - 1);

    // block covers 2048 consecutive rows; wave w owns 512 of them
    const long long rowBase = (long long)b * NVAL
                            + (long long)blk * (ROWS_PER_CHUNK * CHUNKS * WAVES)
                            + (long long)wave * (ROWS_PER_CHUNK * CHUNKS);
    const float4* __restrict__ src0 = (const float4*)(in + rowBase * C_OLD);

    float4* dstv = (float4*)lds[wave];
    const float* row = lds[wave] + lane * C_OLD;      // stride 23: 2-way LDS alias, free

    float acc[G];
    #pragma unroll
    for (int g = 0; g < G; ++g) acc[g] = 0.0f;

    float4 r0, r1, r2, r3, r4, r5;

    // ---- prologue: chunk 0 -> regs -> LDS (same-wave DS is in-order; no barrier) ----
    {
        const float4* s = src0;
        r0 = s[lane];        r1 = s[lane + 64];   r2 = s[lane + 128];
        r3 = s[lane + 192];  r4 = s[lane + 256];
        if (lane < CHUNK_VEC4 - 320) r5 = s[lane + 320];
        dstv[lane] = r0;         dstv[lane + 64] = r1;   dstv[lane + 128] = r2;
        dstv[lane + 192] = r3;   dstv[lane + 256] = r4;
        if (lane < CHUNK_VEC4 - 320) dstv[lane + 320] = r5;
    }

    for (int c = 0; c < CHUNKS; ++c) {
        // ---- prefetch chunk c+1 into registers (in flight during compute) ----
        if (c + 1 < CHUNKS) {
            const float4* s = src0 + (c + 1) * CHUNK_VEC4;
            r0 = s[lane];        r1 = s[lane + 64];   r2 = s[lane + 128];
            r3 = s[lane + 192];  r4 = s[lane + 256];
            if (lane < CHUNK_VEC4 - 320) r5 = s[lane + 320];
        }

        // ---- per-row group sums + normalize ----
        float s0 = row[0] + row[1];
        float s1 = row[2] + row[3];
        float s2 = row[4] + row[5] + row[6];
        float s3 = row[7] + row[8];
        float s4 = row[9] + row[10] + row[11];
        float s5 = row[12] + row[13];
        float s6 = row[14] + row[15] + row[16];
        float s7 = row[17] + row[18];
        float s8 = row[19] + row[20];
        float s9 = row[21] + row[22];
        float tot = ((s0 + s1) + (s2 + s3)) + ((s4 + s5) + (s6 + s7)) + (s8 + s9);
        float inv = 1.0f / tot;
        acc[0] += s0 * inv; acc[1] += s1 * inv; acc[2] += s2 * inv;
        acc[3] += s3 * inv; acc[4] += s4 * inv; acc[5] += s5 * inv;
        acc[6] += s6 * inv; acc[7] += s7 * inv; acc[8] += s8 * inv;
        acc[9] += s9 * inv;

        // ---- write prefetched chunk over our wave-private region.
        // DS pipe is in-order per wave: the reads above already issued, so
        // write-after-read is safe without any barrier. ----
        if (c + 1 < CHUNKS) {
            dstv[lane] = r0;         dstv[lane + 64] = r1;   dstv[lane + 128] = r2;
            dstv[lane + 192] = r3;   dstv[lane + 256] = r4;
            if (lane < CHUNK_VEC4 - 320) dstv[lane + 320] = r5;
        }
    }

    // ---- wave shuffle reduction (512 rows/wave), then cross-wave via LDS ----
    #pragma unroll
    for (int g = 0; g < G; ++g) {
        float v = acc[g];
        #pragma unroll
        for (int off = 32; off > 0; off >>= 1)
            v += __shfl_down(v, off, 64);
        acc[g] = v;
    }
    if (lane == 0) {
        #pragma unroll
        for (int g = 0; g < G; ++g) wpart[wave][g] = acc[g];
    }
    __syncthreads();
    if (tid < G) {
        float s = wpart[0][tid] + wpart[1][tid] + wpart[2][tid] + wpart[3][tid];
        part[((long long)b * G + tid) * BLOCKS_PER_B + blk] = s;
    }
}

__global__ void finalize_kernel(const float* __restrict__ part,
                                const float* __restrict__ tgt,
                                float* __restrict__ out) {
    __shared__ double red[128];
    const int t = threadIdx.x;
    double term = 0.0;
    if (t < BVAL * G) {
        const float4* p4 = (const float4*)(part + (long long)t * BLOCKS_PER_B);
        double s = 0.0;
        #pragma unroll 8
        for (int i = 0; i < BLOCKS_PER_B / 4; ++i) {
            float4 v = p4[i];
            s += (double)v.x + (double)v.y + (double)v.z + (double)v.w;
        }
        double avg = s / (double)NVAL;          // mean prob over N
        double tv  = (double)tgt[t];
        term = tv * (log(tv) - log(avg));
    }
    red[t] = term;
    __syncthreads();
    #pragma unroll
    for (int s = 64; s > 0; s >>= 1) {
        if (t < s) red[t] += red[t + s];
        __syncthreads();
    }
    if (t == 0) out[0] = (float)(red[0] / (double)(G * BVAL));
}

extern "C" void kernel_launch(void* const* d_in, const int* in_sizes, int n_in,
                              void* d_out, int out_size, void* d_ws, size_t ws_size,
                              hipStream_t stream) {
    const float* inputs  = (const float*)d_in[0];   // [8, 262144, 23] f32
    const float* targets = (const float*)d_in[1];   // [8, 10] f32
    float* out  = (float*)d_out;                    // scalar f32
    float* part = (float*)d_ws;                     // 80 * 128 floats

    group_prob_partial_kernel<<<NBLOCKS, BLOCK, 0, stream>>>(inputs, part);
    finalize_kernel<<<1, 128, 0, stream>>>(part, targets, out);
}

// Round 5
// 267.109 us; speedup vs baseline: 1.6153x; 1.0025x over previous
//
#include <hip/hip_runtime.h>
#include <math.h>

#define C_OLD 23
#define G 10
#define BVAL 8
#define NVAL 262144                  // 2^18 rows per b
#define BLOCK 256
#define WAVES (BLOCK / 64)           // 4
#define ROWS_PER_CHUNK 64            // rows per wave per chunk (1 row/lane)
#define CHUNKS 8                     // chunks per wave -> 512 rows/wave, 2048/block
#define BLOCKS_PER_B 128             // 128 * 2048 = 262144 rows = N
#define NBLOCKS (BVAL * BLOCKS_PER_B)          // 1024
#define CHUNK_FLOATS (ROWS_PER_CHUNK * C_OLD)  // 1472 floats = 5888 B per wave
#define CHUNK_VEC4 (CHUNK_FLOATS / 4)          // 368 float4 per chunk
#define REM (CHUNK_VEC4 - 5 * 64)              // 48

struct Frag { float4 r0, r1, r2, r3, r4, r5; };

__device__ __forceinline__ Frag load_chunk(const float4* __restrict__ s, int lane) {
    Frag f;
    f.r0 = s[lane];        f.r1 = s[lane + 64];   f.r2 = s[lane + 128];
    f.r3 = s[lane + 192];  f.r4 = s[lane + 256];
    if (lane < REM) f.r5 = s[lane + 320];
    return f;
}

__device__ __forceinline__ void store_chunk(float4* d, int lane, const Frag& f) {
    d[lane] = f.r0;        d[lane + 64] = f.r1;   d[lane + 128] = f.r2;
    d[lane + 192] = f.r3;  d[lane + 256] = f.r4;
    if (lane < REM) d[lane + 320] = f.r5;
}

__device__ __forceinline__ void accum_row(const float* __restrict__ row, float* acc) {
    float s0 = row[0] + row[1];
    float s1 = row[2] + row[3];
    float s2 = row[4] + row[5] + row[6];
    float s3 = row[7] + row[8];
    float s4 = row[9] + row[10] + row[11];
    float s5 = row[12] + row[13];
    float s6 = row[14] + row[15] + row[16];
    float s7 = row[17] + row[18];
    float s8 = row[19] + row[20];
    float s9 = row[21] + row[22];
    float tot = ((s0 + s1) + (s2 + s3)) + ((s4 + s5) + (s6 + s7)) + (s8 + s9);
    float inv = 1.0f / tot;
    acc[0] += s0 * inv; acc[1] += s1 * inv; acc[2] += s2 * inv;
    acc[3] += s3 * inv; acc[4] += s4 * inv; acc[5] += s5 * inv;
    acc[6] += s6 * inv; acc[7] += s7 * inv; acc[8] += s8 * inv;
    acc[9] += s9 * inv;
}

// ws layout: part[(b*G + g) * BLOCKS_PER_B + blk]  -> 80*128 floats = 40960 B
__global__ __launch_bounds__(BLOCK) void group_prob_partial_kernel(
        const float* __restrict__ in, float* __restrict__ part) {
    __shared__ float lds[WAVES][CHUNK_FLOATS];   // wave-private: no barriers in loop
    __shared__ float wpart[WAVES][G];

    const int tid  = threadIdx.x;
    const int wave = tid >> 6;
    const int lane = tid & 63;
    const int b    = blockIdx.x >> 7;                 // BLOCKS_PER_B == 128
    const int blk  = blockIdx.x & (BLOCKS_PER_B - 1);

    const long long rowBase = (long long)b * NVAL
                            + (long long)blk * (ROWS_PER_CHUNK * CHUNKS * WAVES)
                            + (long long)wave * (ROWS_PER_CHUNK * CHUNKS);
    const float4* __restrict__ src0 = (const float4*)(in + rowBase * C_OLD);

    float4* dstv = (float4*)lds[wave];
    const float* row = lds[wave] + lane * C_OLD;      // stride 23: 2-way alias, free

    float acc[G];
    #pragma unroll
    for (int g = 0; g < G; ++g) acc[g] = 0.0f;

    // ---- distance-2 prefetch: two register sets, single wave-private buffer.
    // Each ds_write waits on loads issued a FULL chunk earlier (vmcnt(6)-style
    // fine-grained wait; no barriers anywhere to force a vmcnt(0) drain).
    // Same-wave DS pipe is in-order: write-after-read needs no sync. ----
    Frag A = load_chunk(src0, lane);                   // chunk 0
    Frag B = load_chunk(src0 + CHUNK_VEC4, lane);      // chunk 1
    store_chunk(dstv, lane, A);                        // waits on A only

    #pragma unroll
    for (int cc = 0; cc < CHUNKS; cc += 2) {
        accum_row(row, acc);                           // chunk cc
        if (cc + 2 < CHUNKS) A = load_chunk(src0 + (cc + 2) * CHUNK_VEC4, lane);
        store_chunk(dstv, lane, B);                    // chunk cc+1 -> LDS (old loads)
        accum_row(row, acc);                           // chunk cc+1
        if (cc + 3 < CHUNKS) B = load_chunk(src0 + (cc + 3) * CHUNK_VEC4, lane);
        if (cc + 2 < CHUNKS) store_chunk(dstv, lane, A);   // chunk cc+2 -> LDS
    }

    // ---- wave shuffle reduction (512 rows/wave), then cross-wave via LDS ----
    #pragma unroll
    for (int g = 0; g < G; ++g) {
        float v = acc[g];
        #pragma unroll
        for (int off = 32; off > 0; off >>= 1)
            v += __shfl_down(v, off, 64);
        acc[g] = v;
    }
    if (lane == 0) {
        #pragma unroll
        for (int g = 0; g < G; ++g) wpart[wave][g] = acc[g];
    }
    __syncthreads();
    if (tid < G) {
        float s = wpart[0][tid] + wpart[1][tid] + wpart[2][tid] + wpart[3][tid];
        part[((long long)b * G + tid) * BLOCKS_PER_B + blk] = s;
    }
}

__global__ void finalize_kernel(const float* __restrict__ part,
                                const float* __restrict__ tgt,
                                float* __restrict__ out) {
    __shared__ double red[128];
    const int t = threadIdx.x;
    double term = 0.0;
    if (t < BVAL * G) {
        const float4* p4 = (const float4*)(part + (long long)t * BLOCKS_PER_B);
        double s = 0.0;
        #pragma unroll 8
        for (int i = 0; i < BLOCKS_PER_B / 4; ++i) {
            float4 v = p4[i];
            s += (double)v.x + (double)v.y + (double)v.z + (double)v.w;
        }
        double avg = s / (double)NVAL;          // mean prob over N
        double tv  = (double)tgt[t];
        term = tv * (log(tv) - log(avg));
    }
    red[t] = term;
    __syncthreads();
    #pragma unroll
    for (int s = 64; s > 0; s >>= 1) {
        if (t < s) red[t] += red[t + s];
        __syncthreads();
    }
    if (t == 0) out[0] = (float)(red[0] / (double)(G * BVAL));
}

extern "C" void kernel_launch(void* const* d_in, const int* in_sizes, int n_in,
                              void* d_out, int out_size, void* d_ws, size_t ws_size,
                              hipStream_t stream) {
    const float* inputs  = (const float*)d_in[0];   // [8, 262144, 23] f32
    const float* targets = (const float*)d_in[1];   // [8, 10] f32
    float* out  = (float*)d_out;                    // scalar f32
    float* part = (float*)d_ws;                     // 80 * 128 floats

    group_prob_partial_kernel<<<NBLOCKS, BLOCK, 0, stream>>>(inputs, part);
    finalize_kernel<<<1, 128, 0, stream>>>(part, targets, out);
}